// Round 4
// baseline (151.216 us; speedup 1.0000x reference)
//
#include <hip/hip_runtime.h>
#include <hip/hip_bf16.h>

// B=4, S=256, H=768, P=54.
// out[b,i,j,p] = valid ? relu(ha[b,i]+hb[b,j]+bp1) . Wp2[p] + bp2[p] : 0
// valid = cand[i] & cand[j] & i!=j; cand = (relu(x W1^T + b1) . W2[0] + b2[0]) > 0.5
// cand rate ~1% -> sparse pairs.
// R1: one block reading all Wp1 = per-CU BW bound -> k-split hab.
// R2: gemm 192 blocks = 1 wave/SIMD -> split-K=4 (768 blocks), stride-68 LDS.
// R3: top dispatches now harness ws-poison fills (43.8us, fixed cost).
//     This round: hab reads Wp1 ONCE (regs, loop slots, atomic acc);
//     gemm LDS double-buffer (1 barrier/iter); pairs+pair fused.

#define M_ROWS 1024
#define HDIM 768
#define PDIM 54
#define MAXC 256
#define KSPLIT 4
#define KSEG (HDIM / KSPLIT)  // 192
#define HKCH 8                // hab k-rows per block

// ---- workspace layout (bytes) ----
#define CANDCNT_OFF  0
#define HA_OFF       4096                    // MAXC*768 f32 = 786432 B
#define HB_OFF       (4096 + 786432)         // 790528
#define ZERO_BYTES   (4096 + 2 * 786432)     // 1576960: candCnt + ha + hb
#define CANDIDX_OFF  1576960                 // MAXC int
#define CANDSLOT_OFF 1577984                 // 1024 int (fully written each call)
#define HPART_OFF    1582080                 // KSPLIT*1024*768 f32 = 12 MB

// ================= split-K GEMM, double-buffered LDS =================
// 64x64 tile, K-seg 192, 256 thr, 4x4 micro. hpart[z][m][n] = partial x.W1^T.
__global__ __launch_bounds__(256) void gemm_k_kernel(
    const float* __restrict__ x, const float* __restrict__ W1,
    float* __restrict__ hpart)
{
    __shared__ float As[2][16][68];
    __shared__ float Bs[2][16][68];

    const int m0 = blockIdx.x * 64;
    const int n0 = blockIdx.y * 64;
    const int kb = blockIdx.z * KSEG;
    const int t  = threadIdx.x;
    const int tm = t & 15;
    const int tn = t >> 4;
    const int r  = t >> 2;        // 0..63
    const int c4 = (t & 3) * 4;   // 0,4,8,12

    const float* xp = x  + (size_t)(m0 + r) * HDIM + kb + c4;
    const float* wp = W1 + (size_t)(n0 + r) * HDIM + kb + c4;

    float acc[4][4] = {};

    float4 av = *(const float4*)xp;
    float4 bv = *(const float4*)wp;
    As[0][c4+0][r] = av.x; As[0][c4+1][r] = av.y; As[0][c4+2][r] = av.z; As[0][c4+3][r] = av.w;
    Bs[0][c4+0][r] = bv.x; Bs[0][c4+1][r] = bv.y; Bs[0][c4+2][r] = bv.z; Bs[0][c4+3][r] = bv.w;
    __syncthreads();

    int buf = 0;
    for (int it = 0; it < KSEG / 16; ++it) {
        if (it < KSEG / 16 - 1) {
            av = *(const float4*)(xp + (it + 1) * 16);   // prefetch next tile
            bv = *(const float4*)(wp + (it + 1) * 16);
        }
        #pragma unroll
        for (int kk = 0; kk < 16; ++kk) {
            float a[4], b[4];
            *(float4*)a = *(const float4*)&As[buf][kk][tm * 4];
            *(float4*)b = *(const float4*)&Bs[buf][kk][tn * 4];
            #pragma unroll
            for (int i = 0; i < 4; ++i)
                #pragma unroll
                for (int j = 0; j < 4; ++j)
                    acc[i][j] += a[i] * b[j];
        }
        if (it < KSEG / 16 - 1) {
            int nb = buf ^ 1;   // writers target other buffer: 1 barrier/iter
            As[nb][c4+0][r] = av.x; As[nb][c4+1][r] = av.y; As[nb][c4+2][r] = av.z; As[nb][c4+3][r] = av.w;
            Bs[nb][c4+0][r] = bv.x; Bs[nb][c4+1][r] = bv.y; Bs[nb][c4+2][r] = bv.z; Bs[nb][c4+3][r] = bv.w;
            buf = nb;
        }
        __syncthreads();
    }

    float* dst = hpart + (size_t)blockIdx.z * (M_ROWS * HDIM);
    #pragma unroll
    for (int i = 0; i < 4; ++i) {
        float4 v = make_float4(acc[i][0], acc[i][1], acc[i][2], acc[i][3]);
        *(float4*)(dst + (size_t)(m0 + tm * 4 + i) * HDIM + n0 + tn * 4) = v;
    }
}

// reduce KSPLIT partials, relu.w2, decide cand. One block per row m.
__global__ __launch_bounds__(256) void span_cand_kernel(
    const float* __restrict__ hpart, const float* __restrict__ b1,
    const float* __restrict__ w2row, const float* __restrict__ b2,
    int* __restrict__ candCount, int* __restrict__ candIdx,
    int* __restrict__ candSlot)
{
    const int m = blockIdx.x;
    const int t = threadIdx.x;
    float p = 0.f;
    for (int n = t; n < HDIM; n += 256) {
        float v = hpart[(size_t)m * HDIM + n]
                + hpart[(size_t)(M_ROWS * HDIM) + (size_t)m * HDIM + n]
                + hpart[(size_t)(2 * M_ROWS * HDIM) + (size_t)m * HDIM + n]
                + hpart[(size_t)(3 * M_ROWS * HDIM) + (size_t)m * HDIM + n];
        v += b1[n];
        v = v > 0.f ? v : 0.f;
        p += v * w2row[n];
    }
    __shared__ float wred[4];
    #pragma unroll
    for (int off = 32; off > 0; off >>= 1) p += __shfl_down(p, off, 64);
    if ((t & 63) == 0) wred[t >> 6] = p;
    __syncthreads();
    if (t == 0) {
        float s = wred[0] + wred[1] + wred[2] + wred[3] + b2[0];
        if (s > 0.5f) {
            int sl = atomicAdd(candCount, 1);
            if (sl < MAXC) { candIdx[sl] = m; candSlot[m] = sl; }
            else candSlot[m] = -1;
        } else {
            candSlot[m] = -1;
        }
    }
}

// ================= hab: Wp1 single-pass =================
// block = (kc 0..95, hseg 0..1). Holds its 8 Wp1 rows' h-half in REGISTERS,
// loops over candidate slots: Wp1 read exactly once total (4.7 MB vs nc*4.7).
// Partial dots (384-wide) accumulated into ha/hb via atomicAdd (f32, ~1e-7 err).
__global__ __launch_bounds__(256) void hab_kernel(
    const float* __restrict__ x, const float* __restrict__ Wp1,
    const int* __restrict__ candCount, const int* __restrict__ candIdx,
    float* __restrict__ ha, float* __restrict__ hb)
{
    int nc = *candCount; if (nc > MAXC) nc = MAXC;
    const int kc   = blockIdx.x >> 1;        // 0..95
    const int hseg = blockIdx.x & 1;         // 0/1
    const int kk   = threadIdx.x >> 5;       // 0..7
    const int lane = threadIdx.x & 31;
    const int k    = kc * HKCH + kk;
    const int hs   = hseg * 384;

    const float* wra = Wp1 + (size_t)k * (2 * HDIM) + hs;
    const float* wrb = wra + HDIM;
    float4 wa0 = *(const float4*)(wra + lane * 4);
    float4 wa1 = *(const float4*)(wra + 128 + lane * 4);
    float4 wa2 = *(const float4*)(wra + 256 + lane * 4);
    float4 wb0 = *(const float4*)(wrb + lane * 4);
    float4 wb1 = *(const float4*)(wrb + 128 + lane * 4);
    float4 wb2 = *(const float4*)(wrb + 256 + lane * 4);

    for (int slot = 0; slot < nc; ++slot) {
        int row = candIdx[slot];
        const float* xr = x + (size_t)row * HDIM + hs;
        float4 x0 = *(const float4*)(xr + lane * 4);
        float4 x1 = *(const float4*)(xr + 128 + lane * 4);
        float4 x2 = *(const float4*)(xr + 256 + lane * 4);
        float sa = wa0.x*x0.x + wa0.y*x0.y + wa0.z*x0.z + wa0.w*x0.w
                 + wa1.x*x1.x + wa1.y*x1.y + wa1.z*x1.z + wa1.w*x1.w
                 + wa2.x*x2.x + wa2.y*x2.y + wa2.z*x2.z + wa2.w*x2.w;
        float sb = wb0.x*x0.x + wb0.y*x0.y + wb0.z*x0.z + wb0.w*x0.w
                 + wb1.x*x1.x + wb1.y*x1.y + wb1.z*x1.z + wb1.w*x1.w
                 + wb2.x*x2.x + wb2.y*x2.y + wb2.z*x2.z + wb2.w*x2.w;
        #pragma unroll
        for (int off = 16; off > 0; off >>= 1) {
            sa += __shfl_down(sa, off, 32);
            sb += __shfl_down(sb, off, 32);
        }
        if (lane == 0) {
            atomicAdd(&ha[(size_t)slot * HDIM + k], sa);
            atomicAdd(&hb[(size_t)slot * HDIM + k], sb);
        }
    }
}

// ================= fused pair scan + logits =================
// 512 blocks x 512 pair-ids each; per-block LDS valid list, then compute.
__global__ __launch_bounds__(256) void pair_kernel(
    const float* __restrict__ ha, const float* __restrict__ hb,
    const float* __restrict__ bp1, const float* __restrict__ Wp2,
    const float* __restrict__ bp2, const int* __restrict__ candSlot,
    float* __restrict__ out)
{
    __shared__ int plist[512];
    __shared__ int pcnt;
    __shared__ float v[HDIM];
    __shared__ float red[4][PDIM + 2];
    const int t = threadIdx.x;
    if (t == 0) pcnt = 0;
    __syncthreads();

    #pragma unroll
    for (int q = 0; q < 2; ++q) {
        int idx = blockIdx.x * 512 + q * 256 + t;  // b*65536 + i*256 + j
        int b = idx >> 16;
        int i = (idx >> 8) & 255;
        int j = idx & 255;
        if (i != j && candSlot[b * 256 + i] >= 0 && candSlot[b * 256 + j] >= 0) {
            int p = atomicAdd(&pcnt, 1);
            plist[p] = idx;
        }
    }
    __syncthreads();
    const int np = pcnt;  // almost always 0 -> block exits immediately

    for (int p = 0; p < np; ++p) {
        int idx = plist[p];
        int b = idx >> 16;
        int i = (idx >> 8) & 255;
        int j = idx & 255;
        int si = candSlot[b * 256 + i];
        int sj = candSlot[b * 256 + j];
        if (t < 192) {
            float4 a4 = *(const float4*)(ha + (size_t)si * HDIM + t * 4);
            float4 b4 = *(const float4*)(hb + (size_t)sj * HDIM + t * 4);
            float4 c4 = *(const float4*)(bp1 + t * 4);
            float4 r;
            r.x = a4.x + b4.x + c4.x; r.x = r.x > 0.f ? r.x : 0.f;
            r.y = a4.y + b4.y + c4.y; r.y = r.y > 0.f ? r.y : 0.f;
            r.z = a4.z + b4.z + c4.z; r.z = r.z > 0.f ? r.z : 0.f;
            r.w = a4.w + b4.w + c4.w; r.w = r.w > 0.f ? r.w : 0.f;
            *(float4*)(v + t * 4) = r;
        }
        __syncthreads();
        if (t < 216) {
            int pp  = t % PDIM;
            int seg = t / PDIM;               // 0..3
            const float* w  = Wp2 + (size_t)pp * HDIM + seg * 192;
            const float* vv = v + seg * 192;
            float s = 0.f;
            for (int h = 0; h < 192; h += 4) {
                float4 a  = *(const float4*)(vv + h);
                float4 b2 = *(const float4*)(w + h);
                s += a.x * b2.x + a.y * b2.y + a.z * b2.z + a.w * b2.w;
            }
            red[seg][pp] = s;
        }
        __syncthreads();
        if (t < PDIM)
            out[(size_t)idx * PDIM + t] = red[0][t] + red[1][t] + red[2][t] + red[3][t] + bp2[t];
        __syncthreads();
    }
}

extern "C" void kernel_launch(void* const* d_in, const int* in_sizes, int n_in,
                              void* d_out, int out_size, void* d_ws, size_t ws_size,
                              hipStream_t stream) {
    const float* x   = (const float*)d_in[0];
    const float* W1s = (const float*)d_in[1];
    const float* b1s = (const float*)d_in[2];
    const float* W2s = (const float*)d_in[3];
    const float* b2s = (const float*)d_in[4];
    const float* Wp1 = (const float*)d_in[5];
    const float* bp1 = (const float*)d_in[6];
    const float* Wp2 = (const float*)d_in[7];
    const float* bp2 = (const float*)d_in[8];

    char* ws = (char*)d_ws;
    int*   candCnt  = (int*)(ws + CANDCNT_OFF);
    float* ha       = (float*)(ws + HA_OFF);
    float* hb       = (float*)(ws + HB_OFF);
    int*   candIdx  = (int*)(ws + CANDIDX_OFF);
    int*   candSlot = (int*)(ws + CANDSLOT_OFF);
    float* hpart    = (float*)(ws + HPART_OFF);
    float* out = (float*)d_out;

    hipMemsetAsync(out, 0, (size_t)out_size * sizeof(float), stream);
    hipMemsetAsync(ws, 0, ZERO_BYTES, stream);  // candCnt + ha + hb

    dim3 g(M_ROWS / 64, HDIM / 64, KSPLIT);
    gemm_k_kernel<<<g, 256, 0, stream>>>(x, W1s, hpart);

    span_cand_kernel<<<M_ROWS, 256, 0, stream>>>(hpart, b1s, W2s, b2s,
                                                 candCnt, candIdx, candSlot);

    hab_kernel<<<192, 256, 0, stream>>>(x, Wp1, candCnt, candIdx, ha, hb);

    pair_kernel<<<512, 256, 0, stream>>>(ha, hb, bp1, Wp2, bp2, candSlot, out);
}

// Round 5
// 147.374 us; speedup vs baseline: 1.0261x; 1.0261x over previous
//
#include <hip/hip_runtime.h>
#include <hip/hip_bf16.h>

// B=4, S=256, H=768, P=54.
// out[b,i,j,p] = valid ? relu(ha[b,i]+hb[b,j]+bp1) . Wp2[p] + bp2[p] : 0
// valid = cand[i] & cand[j] & i!=j; cand = (relu(x W1^T + b1) . W2[0] + b2[0]) > 0.5
// cand rate ~1% -> sparse pairs.
// R1: one block reading all Wp1 = per-CU BW bound -> k-split hab.
// R2: gemm 192 blocks = 1 wave/SIMD -> split-K=4 (768 blocks), stride-68 LDS.
// R3: 139.8us, top = harness ws-poison fills (43.8us fixed).
// R4: +11us REGRESSION (db-gemm + 192-blk hab + fused pair, unattributed).
// R5: revert gemm to proven R3 single-buffer; hab = register-resident Wp1
//     single pass, no atomics; pair_kernel self-zeroes its out region.
//     Dispatches 6 -> 4 (no memsets).

#define M_ROWS 1024
#define HDIM 768
#define PDIM 54
#define MAXC 256
#define KSPLIT 4
#define KSEG (HDIM / KSPLIT)  // 192

// ---- workspace layout (bytes) ----
#define CANDCNT_OFF  0
#define CANDIDX_OFF  1024                    // MAXC int
#define CANDSLOT_OFF 8192                    // 1024 int (fully written each call)
#define HA_OFF       16384                   // MAXC*768 f32 = 786432 B
#define HB_OFF       (16384 + 786432)
#define HPART_OFF    (16384 + 2 * 786432)    // KSPLIT*1024*768 f32 = 12 MB

// ================= split-K GEMM (R3-proven single-buffer) =================
// 64x64 tile, K-seg 192, 256 thr, 4x4 micro. hpart[z][m][n] = partial x.W1^T.
// Thread (0,0,0,0) also zeroes candCnt (ws is 0xAA-poisoned before every call).
__global__ __launch_bounds__(256) void gemm_k_kernel(
    const float* __restrict__ x, const float* __restrict__ W1,
    float* __restrict__ hpart, int* __restrict__ candCnt)
{
    __shared__ float As[16][68];
    __shared__ float Bs[16][68];

    if (threadIdx.x == 0 && blockIdx.x == 0 && blockIdx.y == 0 && blockIdx.z == 0)
        *candCnt = 0;

    const int m0 = blockIdx.x * 64;
    const int n0 = blockIdx.y * 64;
    const int kb = blockIdx.z * KSEG;
    const int t  = threadIdx.x;
    const int tm = t & 15;
    const int tn = t >> 4;
    const int r  = t >> 2;        // 0..63
    const int c4 = (t & 3) * 4;   // 0,4,8,12

    float acc[4][4] = {};

    for (int k0 = kb; k0 < kb + KSEG; k0 += 16) {
        float4 av = *(const float4*)(x  + (size_t)(m0 + r) * HDIM + k0 + c4);
        float4 bv = *(const float4*)(W1 + (size_t)(n0 + r) * HDIM + k0 + c4);
        As[c4+0][r] = av.x; As[c4+1][r] = av.y; As[c4+2][r] = av.z; As[c4+3][r] = av.w;
        Bs[c4+0][r] = bv.x; Bs[c4+1][r] = bv.y; Bs[c4+2][r] = bv.z; Bs[c4+3][r] = bv.w;
        __syncthreads();
        #pragma unroll
        for (int kk = 0; kk < 16; ++kk) {
            float a[4], b[4];
            *(float4*)a = *(const float4*)&As[kk][tm * 4];
            *(float4*)b = *(const float4*)&Bs[kk][tn * 4];
            #pragma unroll
            for (int i = 0; i < 4; ++i)
                #pragma unroll
                for (int j = 0; j < 4; ++j)
                    acc[i][j] += a[i] * b[j];
        }
        __syncthreads();
    }

    float* dst = hpart + (size_t)blockIdx.z * (M_ROWS * HDIM);
    #pragma unroll
    for (int i = 0; i < 4; ++i) {
        float4 v = make_float4(acc[i][0], acc[i][1], acc[i][2], acc[i][3]);
        *(float4*)(dst + (size_t)(m0 + tm * 4 + i) * HDIM + n0 + tn * 4) = v;
    }
}

// reduce KSPLIT partials, relu.w2, decide cand. One block per row m.
__global__ __launch_bounds__(256) void span_cand_kernel(
    const float* __restrict__ hpart, const float* __restrict__ b1,
    const float* __restrict__ w2row, const float* __restrict__ b2,
    int* __restrict__ candCount, int* __restrict__ candIdx,
    int* __restrict__ candSlot)
{
    const int m = blockIdx.x;
    const int t = threadIdx.x;
    float p = 0.f;
    for (int n = t; n < HDIM; n += 256) {
        float v = hpart[(size_t)m * HDIM + n]
                + hpart[(size_t)(M_ROWS * HDIM) + (size_t)m * HDIM + n]
                + hpart[(size_t)(2 * M_ROWS * HDIM) + (size_t)m * HDIM + n]
                + hpart[(size_t)(3 * M_ROWS * HDIM) + (size_t)m * HDIM + n];
        v += b1[n];
        v = v > 0.f ? v : 0.f;
        p += v * w2row[n];
    }
    __shared__ float wred[4];
    #pragma unroll
    for (int off = 32; off > 0; off >>= 1) p += __shfl_down(p, off, 64);
    if ((t & 63) == 0) wred[t >> 6] = p;
    __syncthreads();
    if (t == 0) {
        float s = wred[0] + wred[1] + wred[2] + wred[3] + b2[0];
        if (s > 0.5f) {
            int sl = atomicAdd(candCount, 1);
            if (sl < MAXC) { candIdx[sl] = m; candSlot[m] = sl; }
            else candSlot[m] = -1;
        } else {
            candSlot[m] = -1;
        }
    }
}

// ================= hab: Wp1 single-pass, register-resident, no atomics ======
// block = kc (0..95): 8 k-rows of Wp1, FULL h in regs (12 float4/thread).
// Loops candidate slots; each ha/hb element written exactly once (no zero-init).
// Wp1 read exactly once total (4.7 MB).
__global__ __launch_bounds__(256) void hab_kernel(
    const float* __restrict__ x, const float* __restrict__ Wp1,
    const int* __restrict__ candCount, const int* __restrict__ candIdx,
    float* __restrict__ ha, float* __restrict__ hb)
{
    int nc = *candCount; if (nc > MAXC) nc = MAXC;
    const int kk   = threadIdx.x >> 5;       // 0..7
    const int lane = threadIdx.x & 31;
    const int k    = blockIdx.x * 8 + kk;    // 0..767

    const float* wr = Wp1 + (size_t)k * (2 * HDIM);
    float4 wa[6], wb[6];
    #pragma unroll
    for (int c = 0; c < 6; ++c) {
        wa[c] = *(const float4*)(wr + c * 128 + lane * 4);
        wb[c] = *(const float4*)(wr + HDIM + c * 128 + lane * 4);
    }

    for (int slot = 0; slot < nc; ++slot) {
        int row = candIdx[slot];
        const float* xr = x + (size_t)row * HDIM;
        float sa = 0.f, sb = 0.f;
        #pragma unroll
        for (int c = 0; c < 6; ++c) {
            float4 xv = *(const float4*)(xr + c * 128 + lane * 4);
            sa += wa[c].x*xv.x + wa[c].y*xv.y + wa[c].z*xv.z + wa[c].w*xv.w;
            sb += wb[c].x*xv.x + wb[c].y*xv.y + wb[c].z*xv.z + wb[c].w*xv.w;
        }
        #pragma unroll
        for (int off = 16; off > 0; off >>= 1) {
            sa += __shfl_down(sa, off, 32);
            sb += __shfl_down(sb, off, 32);
        }
        if (lane == 0) {
            ha[(size_t)slot * HDIM + k] = sa;
            hb[(size_t)slot * HDIM + k] = sb;
        }
    }
}

// ================= fused zero + pair scan + logits =================
// Each block OWNS pair-id range [bid*512, bid*512+512): zeroes its out region
// (disjoint across blocks), scans for valid pairs, computes them.
// __syncthreads orders zero-stores before value-stores within the block.
__global__ __launch_bounds__(256) void pair_kernel(
    const float* __restrict__ ha, const float* __restrict__ hb,
    const float* __restrict__ bp1, const float* __restrict__ Wp2,
    const float* __restrict__ bp2, const int* __restrict__ candSlot,
    float* __restrict__ out)
{
    __shared__ int plist[512];
    __shared__ int pcnt;
    __shared__ float v[HDIM];
    __shared__ float red[4][PDIM + 2];
    const int t = threadIdx.x;

    // zero own region: 512 pairs * 54 f32 = 6912 float4
    float* outb = out + (size_t)blockIdx.x * 512 * PDIM;
    float4 z = make_float4(0.f, 0.f, 0.f, 0.f);
    #pragma unroll
    for (int q = 0; q < 27; ++q)
        *(float4*)(outb + (size_t)(q * 256 + t) * 4) = z;

    if (t == 0) pcnt = 0;
    __syncthreads();

    #pragma unroll
    for (int q = 0; q < 2; ++q) {
        int idx = blockIdx.x * 512 + q * 256 + t;  // b*65536 + i*256 + j
        int b = idx >> 16;
        int i = (idx >> 8) & 255;
        int j = idx & 255;
        if (i != j && candSlot[b * 256 + i] >= 0 && candSlot[b * 256 + j] >= 0) {
            int p = atomicAdd(&pcnt, 1);
            plist[p] = idx;
        }
    }
    __syncthreads();   // also drains zero-stores (vmcnt(0) before barrier)
    const int np = pcnt;  // almost always 0 -> block exits after ~zeroing

    for (int p = 0; p < np; ++p) {
        int idx = plist[p];
        int b = idx >> 16;
        int i = (idx >> 8) & 255;
        int j = idx & 255;
        int si = candSlot[b * 256 + i];
        int sj = candSlot[b * 256 + j];
        if (t < 192) {
            float4 a4 = *(const float4*)(ha + (size_t)si * HDIM + t * 4);
            float4 b4 = *(const float4*)(hb + (size_t)sj * HDIM + t * 4);
            float4 c4 = *(const float4*)(bp1 + t * 4);
            float4 r;
            r.x = a4.x + b4.x + c4.x; r.x = r.x > 0.f ? r.x : 0.f;
            r.y = a4.y + b4.y + c4.y; r.y = r.y > 0.f ? r.y : 0.f;
            r.z = a4.z + b4.z + c4.z; r.z = r.z > 0.f ? r.z : 0.f;
            r.w = a4.w + b4.w + c4.w; r.w = r.w > 0.f ? r.w : 0.f;
            *(float4*)(v + t * 4) = r;
        }
        __syncthreads();
        if (t < 216) {
            int pp  = t % PDIM;
            int seg = t / PDIM;               // 0..3
            const float* w  = Wp2 + (size_t)pp * HDIM + seg * 192;
            const float* vv = v + seg * 192;
            float s = 0.f;
            for (int h = 0; h < 192; h += 4) {
                float4 a  = *(const float4*)(vv + h);
                float4 b2 = *(const float4*)(w + h);
                s += a.x * b2.x + a.y * b2.y + a.z * b2.z + a.w * b2.w;
            }
            red[seg][pp] = s;
        }
        __syncthreads();
        if (t < PDIM)
            out[(size_t)idx * PDIM + t] = red[0][t] + red[1][t] + red[2][t] + red[3][t] + bp2[t];
        __syncthreads();
    }
}

extern "C" void kernel_launch(void* const* d_in, const int* in_sizes, int n_in,
                              void* d_out, int out_size, void* d_ws, size_t ws_size,
                              hipStream_t stream) {
    const float* x   = (const float*)d_in[0];
    const float* W1s = (const float*)d_in[1];
    const float* b1s = (const float*)d_in[2];
    const float* W2s = (const float*)d_in[3];
    const float* b2s = (const float*)d_in[4];
    const float* Wp1 = (const float*)d_in[5];
    const float* bp1 = (const float*)d_in[6];
    const float* Wp2 = (const float*)d_in[7];
    const float* bp2 = (const float*)d_in[8];

    char* ws = (char*)d_ws;
    int*   candCnt  = (int*)(ws + CANDCNT_OFF);
    int*   candIdx  = (int*)(ws + CANDIDX_OFF);
    int*   candSlot = (int*)(ws + CANDSLOT_OFF);
    float* ha       = (float*)(ws + HA_OFF);
    float* hb       = (float*)(ws + HB_OFF);
    float* hpart    = (float*)(ws + HPART_OFF);
    float* out = (float*)d_out;

    dim3 g(M_ROWS / 64, HDIM / 64, KSPLIT);
    gemm_k_kernel<<<g, 256, 0, stream>>>(x, W1s, hpart, candCnt);

    span_cand_kernel<<<M_ROWS, 256, 0, stream>>>(hpart, b1s, W2s, b2s,
                                                 candCnt, candIdx, candSlot);

    hab_kernel<<<96, 256, 0, stream>>>(x, Wp1, candCnt, candIdx, ha, hb);

    pair_kernel<<<512, 256, 0, stream>>>(ha, hb, bp1, Wp2, bp2, candSlot, out);
}